// Round 11
// baseline (213.429 us; speedup 1.0000x reference)
//
#include <hip/hip_runtime.h>
#include <hip/hip_bf16.h>
#include <math.h>

#define B_ 4
#define F_ 256
#define C_ 19
#define S_ 256
#define N_ 16384
#define M_ 9728
#define MT_ 38           // m-tiles (256 cols each) in pass1
#define GEMM_BLKS 4864   // 38 mt * 128 nt
#define T_BLOCKS 256     // k_terms blocks (64 pixels each)

typedef __bf16 bf16_t;
typedef bf16_t bf16x8 __attribute__((ext_vector_type(8)));
typedef float floatx4 __attribute__((ext_vector_type(4)));

#define AS1 __attribute__((address_space(1)))
#define AS3 __attribute__((address_space(3)))

// Fragment-order layout (validated r5-r10): element (row, f) lives at
//   ((row>>4)*8 + (f>>5))*512 + ((f>>3)&3)*128 + (row&15)*8 + (f&7)
// fragment (16-row group g, k-step kt) = contiguous 1 KB at (g*8+kt)*512,
// ordered lane*8 with lane=(kchunk<<4)|row.
__device__ inline size_t fragoff(int row, int f) {
    return ((size_t)((row >> 4) * 8 + (f >> 5))) * 512
         + (size_t)((((f >> 3) & 3) * 128) + ((row & 15) * 8) + (f & 7));
}

// ---------------- kernel 1: prep (pure convert; block 0 zeroes control) ----------
__global__ __launch_bounds__(256) void k_prep(const float* __restrict__ pred,
                                              const float* __restrict__ mem,
                                              __hip_bfloat16* __restrict__ A16f,
                                              __hip_bfloat16* __restrict__ B16,
                                              int* __restrict__ ctrl) {
    int bid = blockIdx.x;
    int t = threadIdx.x;
    if (bid < 256) {
        __shared__ float part[4][64];
        __shared__ float invf_s[64];
        if (bid == 0 && t < 40) ctrl[t] = 0;      // done + class_sum[19] + class_cnt[19]
        int b = bid >> 6, hw0 = (bid & 63) * 64;
        int j = t & 63, q = t >> 6;
        int n0 = b * 4096 + hw0;

        const float* base = pred + ((size_t)b * F_ + q * 64) * 4096 + hw0 + j;
        float v[64];
        float s = 0.f;
        #pragma unroll
        for (int i = 0; i < 64; ++i) {
            float x = base[(size_t)i * 4096];
            v[i] = x;
            s += x * x;
        }
        part[q][j] = s;
        __syncthreads();
        if (t < 64) invf_s[t] = 1.0f / sqrtf(part[0][t] + part[1][t] + part[2][t] + part[3][t]);
        __syncthreads();
        float invf = invf_s[j];
        #pragma unroll
        for (int c = 0; c < 8; ++c) {
            int f = q * 64 + c * 8;
            __hip_bfloat16 tmp[8];
            #pragma unroll
            for (int u = 0; u < 8; ++u) tmp[u] = __float2bfloat16(v[c * 8 + u] * invf);
            *(float4*)&A16f[fragoff(n0 + j, f)] = *(float4*)tmp;
        }
    } else {
        int row  = (bid - 256) * 4 + (t >> 6);
        int lane = t & 63;
        float4 a = ((const float4*)(mem + (size_t)row * F_))[lane];
        float s = a.x*a.x + a.y*a.y + a.z*a.z + a.w*a.w;
        #pragma unroll
        for (int off = 32; off; off >>= 1) s += __shfl_xor(s, off, 64);
        float invm = 1.0f / sqrtf(s);
        __hip_bfloat16 tmp[4];
        tmp[0] = __float2bfloat16(a.x * invm);
        tmp[1] = __float2bfloat16(a.y * invm);
        tmp[2] = __float2bfloat16(a.z * invm);
        tmp[3] = __float2bfloat16(a.w * invm);
        *(float2*)&B16[fragoff(row, lane * 4)] = *(float2*)tmp;
    }
}

// ---------------- kernel 2: pass-1 GEMM 128n x 256m + own-class E scatter ----------
// grid 4864, 512 thr = 8 waves of 64x64.  XCD-aware decode clusters same-mt
// blocks per XCD.  A panel (64 KB contiguous frag-order) staged once via
// global_load_lds; zero-barrier K-loop; B register-direct.  Epilogue: row sums
// -> totpart (one slot per mt); rows whose label owns this m-tile (cls = mt>>1)
// scatter their 256 E values as bf16 into classbuf.
__global__ __launch_bounds__(512, 4) void k_pass1(const __hip_bfloat16* __restrict__ A16f,
                                                  const __hip_bfloat16* __restrict__ B16,
                                                  const int* __restrict__ labels,
                                                  float* __restrict__ totpart,
                                                  __hip_bfloat16* __restrict__ classbuf) {
    __shared__ __hip_bfloat16 As[128 * 256];     // 64 KB
    __shared__ float totals_s[4][128];
    __shared__ int lab_s[128];
    int t = threadIdx.x;
    int w = t >> 6, lane = t & 63;
    int bid = blockIdx.x;
    int xcd = bid & 7, j = bid >> 3;
    int mt = j >> 4;                             // 0..37
    int nt = ((j & 15) << 3) | xcd;              // 0..127
    int n0 = nt * 128, m0 = mt * 256;
    int nh = w & 1, mq = w >> 1;

    if (t < 128) lab_s[t] = labels[n0 + t];

    // stage A panel: 64 KB contiguous, wave w does [w*4096, w*4096+4096) elems
    {
        const __hip_bfloat16* src = A16f + ((size_t)n0 << 8) + w * 4096 + lane * 8;
        __hip_bfloat16* dst = &As[w * 4096];
        #pragma unroll
        for (int i = 0; i < 8; ++i)
            __builtin_amdgcn_global_load_lds((const AS1 unsigned int*)(src + i * 512),
                                             (AS3 unsigned int*)(dst + i * 512), 16, 0, 0);
    }
    __syncthreads();

    floatx4 acc[4][4];
    #pragma unroll
    for (int i = 0; i < 4; ++i)
        #pragma unroll
        for (int j2 = 0; j2 < 4; ++j2) acc[i][j2] = (floatx4){0.f, 0.f, 0.f, 0.f};

    const bf16x8* Bp = (const bf16x8*)B16 + ((size_t)((m0 >> 4) + mq * 4) * 8) * 64 + lane;

    #pragma unroll
    for (int kt = 0; kt < 8; ++kt) {
        bf16x8 af[4], bfr[4];
        #pragma unroll
        for (int ni = 0; ni < 4; ++ni)
            af[ni] = *(const bf16x8*)&As[((nh * 4 + ni) * 8 + kt) * 512 + lane * 8];
        #pragma unroll
        for (int mi = 0; mi < 4; ++mi)
            bfr[mi] = Bp[(size_t)(mi * 8 + kt) * 64];
        #pragma unroll
        for (int ni = 0; ni < 4; ++ni)
            #pragma unroll
            for (int mi = 0; mi < 4; ++mi)
                acc[ni][mi] = __builtin_amdgcn_mfma_f32_16x16x32_bf16(af[ni], bfr[mi], acc[ni][mi], 0, 0, 0);
    }

    // epilogue: E = exp(2*cos); row sums + own-class bf16 scatter
    int colL = lane & 15, rgrp = (lane >> 4) * 4;
    int cls = mt >> 1;
    int cib = (mt & 1) * 256 + mq * 64 + colL;   // col within the class's 512-block
    float racc[4][4];
    #pragma unroll
    for (int ni = 0; ni < 4; ++ni)
        #pragma unroll
        for (int r = 0; r < 4; ++r) racc[ni][r] = 0.f;
    #pragma unroll
    for (int ni = 0; ni < 4; ++ni)
        #pragma unroll
        for (int r = 0; r < 4; ++r) {
            int row = nh * 64 + ni * 16 + rgrp + r;
            bool sel = (lab_s[row] == cls);
            size_t ebase = (size_t)(n0 + row) * 512 + cib;
            #pragma unroll
            for (int mi = 0; mi < 4; ++mi) {
                float e = __expf(2.0f * acc[ni][mi][r]);
                racc[ni][r] += e;
                if (sel) classbuf[ebase + mi * 16] = __float2bfloat16(e);
            }
        }

    #pragma unroll
    for (int ni = 0; ni < 4; ++ni)
        #pragma unroll
        for (int r = 0; r < 4; ++r) {
            float s = racc[ni][r];
            s += __shfl_xor(s, 1, 64);
            s += __shfl_xor(s, 2, 64);
            s += __shfl_xor(s, 4, 64);
            s += __shfl_xor(s, 8, 64);
            if (colL == 0) totals_s[mq][nh * 64 + ni * 16 + rgrp + r] = s;
        }
    __syncthreads();
    if (t < 128)
        totpart[(size_t)mt * N_ + n0 + t] =
            totals_s[0][t] + totals_s[1][t] + totals_s[2][t] + totals_s[3][t];
}

// ---------------- kernel 3: per-pixel terms + class bins + fused final ----------
// 256 blocks x 512 thr = 8 waves; wave ws handles pixels n0+ws*8..+8.  Per pixel:
// one coalesced 1 KB classbuf read, 38-slot totpart sum in-wave, exact fp32 log
// terms on the wm-selected half.  Per-block LDS 19-bin reduce -> <=19 global
// atomics; done-counter; last block computes the loss.
__global__ __launch_bounds__(512) void k_terms(const __hip_bfloat16* __restrict__ classbuf,
                                               const float* __restrict__ totpart,
                                               const int* __restrict__ labels,
                                               const int* __restrict__ mask,
                                               const int* __restrict__ wmem,
                                               int* __restrict__ done,
                                               float* __restrict__ class_sum,
                                               int* __restrict__ class_cnt,
                                               float* __restrict__ out) {
    __shared__ float csum_s[C_];
    __shared__ int ccnt_s[C_];
    int t = threadIdx.x, ws = t >> 6, lane = t & 63;
    int n0 = blockIdx.x * 64;
    if (t < C_) { csum_s[t] = 0.f; ccnt_s[t] = 0; }
    __syncthreads();

    for (int q = 0; q < 8; ++q) {
        int n = n0 + ws * 8 + q;
        if (!mask[n]) continue;
        int wm = wmem[n];
        int lab = labels[n];
        bf16x8 ev = *(const bf16x8*)&classbuf[(size_t)n * 512 + lane * 8];
        float vv[8];
        #pragma unroll
        for (int u = 0; u < 8; ++u) vv[u] = (float)ev[u];
        float bs = vv[0] + vv[1] + vv[2] + vv[3] + vv[4] + vv[5] + vv[6] + vv[7];
        float tp = (lane < MT_) ? totpart[(size_t)lane * N_ + n] : 0.f;
        #pragma unroll
        for (int off = 1; off < 64; off <<= 1) {
            bs += __shfl_xor(bs, off, 64);
            tp += __shfl_xor(tp, off, 64);
        }
        float down = tp - bs;
        int lo = (wm == 1) ? 0 : 32;                // wm==1 -> first half [0,S)
        float ts = 0.f;
        if (lane >= lo && lane < lo + 32) {
            #pragma unroll
            for (int u = 0; u < 8; ++u) {
                float pv = vv[u];
                ts += -logf(pv / (pv + down + 1e-12f) + 1e-12f);
            }
        }
        #pragma unroll
        for (int off = 1; off < 64; off <<= 1) ts += __shfl_xor(ts, off, 64);
        if (lane == 0) {
            atomicAdd(&csum_s[lab], ts);
            atomicAdd(&ccnt_s[lab], 1);
        }
    }
    __syncthreads();
    if (t < C_) {
        if (ccnt_s[t] > 0) {
            atomicAdd(&class_sum[t], csum_s[t]);
            atomicAdd(&class_cnt[t], ccnt_s[t]);
        }
    }
    __syncthreads();
    if (t == 0) {
        __threadfence();
        int old = atomicAdd(done, 1);
        if (old == T_BLOCKS - 1) {
            float loss = 0.f, kc = 0.f;
            for (int c = 0; c < C_; ++c) {
                int cn = atomicAdd(&class_cnt[c], 0);
                float sc = atomicAdd(&class_sum[c], 0.f);
                if (cn > 0) { loss += sc / ((float)cn * (float)S_); kc += 1.f; }
            }
            out[0] = loss / fmaxf(kc, 1.f);
        }
    }
}

extern "C" void kernel_launch(void* const* d_in, const int* in_sizes, int n_in,
                              void* d_out, int out_size, void* d_ws, size_t ws_size,
                              hipStream_t stream) {
    const float* mem    = (const float*)d_in[0];
    const float* pred   = (const float*)d_in[1];
    const int*   labels = (const int*)  d_in[2];
    const int*   mask   = (const int*)  d_in[3];
    const int*   wmem   = (const int*)  d_in[4];
    float* out = (float*)d_out;

    float* ws = (float*)d_ws;
    float* totpart   = ws;                            // 38*N_ = 622,592 floats
    int*   ctrl      = (int*)(ws + 622592);           // 40 words
    int*   done      = ctrl;                          // 1
    float* class_sum = (float*)(ctrl + 1);            // 19
    int*   class_cnt = ctrl + 20;                     // 19
    __hip_bfloat16* classbuf = (__hip_bfloat16*)(ws + 622640);   // 16.78 MB bf16
    __hip_bfloat16* A16f = (__hip_bfloat16*)(ws + 4816944);      // 8 MB (frag order)
    __hip_bfloat16* B16  = (__hip_bfloat16*)(ws + 6914096);      // 4.98 MB (frag order)

    k_prep<<<256 + M_ / 4, 256, 0, stream>>>(pred, mem, A16f, B16, ctrl);

    k_pass1<<<GEMM_BLKS, 512, 0, stream>>>(A16f, B16, labels, totpart, classbuf);

    k_terms<<<T_BLOCKS, 512, 0, stream>>>(classbuf, totpart, labels, mask, wmem,
                                          done, class_sum, class_cnt, out);
}

// Round 12
// 213.342 us; speedup vs baseline: 1.0004x; 1.0004x over previous
//
#include <hip/hip_runtime.h>
#include <hip/hip_bf16.h>
#include <math.h>

#define B_ 4
#define F_ 256
#define C_ 19
#define S_ 256
#define N_ 16384
#define M_ 9728
#define MT_ 38           // m-tiles (256 cols each) in pass1
#define GEMM_BLKS 4864   // 38 mt * 128 nt
#define T_BLOCKS 256     // k_terms blocks (64 pixels each)

typedef __bf16 bf16_t;
typedef bf16_t bf16x8 __attribute__((ext_vector_type(8)));
typedef float floatx4 __attribute__((ext_vector_type(4)));

#define AS1 __attribute__((address_space(1)))
#define AS3 __attribute__((address_space(3)))

// Fragment-order layout (validated r5-r11): element (row, f) lives at
//   ((row>>4)*8 + (f>>5))*512 + ((f>>3)&3)*128 + (row&15)*8 + (f&7)
// fragment (16-row group g, k-step kt) = contiguous 1 KB at (g*8+kt)*512,
// ordered lane*8 with lane=(kchunk<<4)|row.
__device__ inline size_t fragoff(int row, int f) {
    return ((size_t)((row >> 4) * 8 + (f >> 5))) * 512
         + (size_t)((((f >> 3) & 3) * 128) + ((row & 15) * 8) + (f & 7));
}

// ---------------- kernel 1: prep (pure convert; block 0 zeroes control) ----------
__global__ __launch_bounds__(256) void k_prep(const float* __restrict__ pred,
                                              const float* __restrict__ mem,
                                              __hip_bfloat16* __restrict__ A16f,
                                              __hip_bfloat16* __restrict__ B16,
                                              int* __restrict__ ctrl) {
    int bid = blockIdx.x;
    int t = threadIdx.x;
    if (bid < 256) {
        __shared__ float part[4][64];
        __shared__ float invf_s[64];
        if (bid == 0 && t < 40) ctrl[t] = 0;      // done + class_sum[19] + class_cnt[19]
        int b = bid >> 6, hw0 = (bid & 63) * 64;
        int j = t & 63, q = t >> 6;
        int n0 = b * 4096 + hw0;

        const float* base = pred + ((size_t)b * F_ + q * 64) * 4096 + hw0 + j;
        float v[64];
        float s = 0.f;
        #pragma unroll
        for (int i = 0; i < 64; ++i) {
            float x = base[(size_t)i * 4096];
            v[i] = x;
            s += x * x;
        }
        part[q][j] = s;
        __syncthreads();
        if (t < 64) invf_s[t] = 1.0f / sqrtf(part[0][t] + part[1][t] + part[2][t] + part[3][t]);
        __syncthreads();
        float invf = invf_s[j];
        #pragma unroll
        for (int c = 0; c < 8; ++c) {
            int f = q * 64 + c * 8;
            __hip_bfloat16 tmp[8];
            #pragma unroll
            for (int u = 0; u < 8; ++u) tmp[u] = __float2bfloat16(v[c * 8 + u] * invf);
            *(float4*)&A16f[fragoff(n0 + j, f)] = *(float4*)tmp;
        }
    } else {
        int row  = (bid - 256) * 4 + (t >> 6);
        int lane = t & 63;
        float4 a = ((const float4*)(mem + (size_t)row * F_))[lane];
        float s = a.x*a.x + a.y*a.y + a.z*a.z + a.w*a.w;
        #pragma unroll
        for (int off = 32; off; off >>= 1) s += __shfl_xor(s, off, 64);
        float invm = 1.0f / sqrtf(s);
        __hip_bfloat16 tmp[4];
        tmp[0] = __float2bfloat16(a.x * invm);
        tmp[1] = __float2bfloat16(a.y * invm);
        tmp[2] = __float2bfloat16(a.z * invm);
        tmp[3] = __float2bfloat16(a.w * invm);
        *(float2*)&B16[fragoff(row, lane * 4)] = *(float2*)tmp;
    }
}

// ---------------- kernel 2: pass-1 GEMM 128n x 256m + own-class E scatter ----------
// grid 4864, 512 thr = 8 waves of 64x64.  XCD-aware decode clusters same-mt
// blocks per XCD.  A panel (64 KB contiguous frag-order) staged once via
// global_load_lds; B register-direct with EXPLICIT one-kt-ahead register
// double-buffer (kt=0 loads issued before the staging barrier).  Epilogue:
// row sums -> atomicAdd total[n]; own-class rows scatter bf16 E -> classbuf.
__global__ __launch_bounds__(512, 4) void k_pass1(const __hip_bfloat16* __restrict__ A16f,
                                                  const __hip_bfloat16* __restrict__ B16,
                                                  const int* __restrict__ labels,
                                                  float* __restrict__ total,
                                                  __hip_bfloat16* __restrict__ classbuf) {
    __shared__ __hip_bfloat16 As[128 * 256];     // 64 KB
    __shared__ float totals_s[4][128];
    __shared__ int lab_s[128];
    int t = threadIdx.x;
    int w = t >> 6, lane = t & 63;
    int bid = blockIdx.x;
    int xcd = bid & 7, j = bid >> 3;
    int mt = j >> 4;                             // 0..37
    int nt = ((j & 15) << 3) | xcd;              // 0..127
    int n0 = nt * 128, m0 = mt * 256;
    int nh = w & 1, mq = w >> 1;

    if (t < 128) lab_s[t] = labels[n0 + t];

    // stage A panel: 64 KB contiguous, wave w does [w*4096, w*4096+4096) elems
    {
        const __hip_bfloat16* src = A16f + ((size_t)n0 << 8) + w * 4096 + lane * 8;
        __hip_bfloat16* dst = &As[w * 4096];
        #pragma unroll
        for (int i = 0; i < 8; ++i)
            __builtin_amdgcn_global_load_lds((const AS1 unsigned int*)(src + i * 512),
                                             (AS3 unsigned int*)(dst + i * 512), 16, 0, 0);
    }

    const bf16x8* Bp = (const bf16x8*)B16 + ((size_t)((m0 >> 4) + mq * 4) * 8) * 64 + lane;

    // kt=0 B fragments issued BEFORE the barrier: they complete during the drain
    bf16x8 bcur[4], bnxt[4];
    #pragma unroll
    for (int mi = 0; mi < 4; ++mi) bcur[mi] = Bp[(size_t)(mi * 8) * 64];

    __syncthreads();

    floatx4 acc[4][4];
    #pragma unroll
    for (int i = 0; i < 4; ++i)
        #pragma unroll
        for (int j2 = 0; j2 < 4; ++j2) acc[i][j2] = (floatx4){0.f, 0.f, 0.f, 0.f};

    #pragma unroll
    for (int kt = 0; kt < 8; ++kt) {
        // prefetch next kt's B fragments before this kt's MFMAs
        if (kt < 7) {
            #pragma unroll
            for (int mi = 0; mi < 4; ++mi)
                bnxt[mi] = Bp[(size_t)(mi * 8 + kt + 1) * 64];
        }
        bf16x8 af[4];
        #pragma unroll
        for (int ni = 0; ni < 4; ++ni)
            af[ni] = *(const bf16x8*)&As[((nh * 4 + ni) * 8 + kt) * 512 + lane * 8];
        #pragma unroll
        for (int ni = 0; ni < 4; ++ni)
            #pragma unroll
            for (int mi = 0; mi < 4; ++mi)
                acc[ni][mi] = __builtin_amdgcn_mfma_f32_16x16x32_bf16(af[ni], bcur[mi], acc[ni][mi], 0, 0, 0);
        if (kt < 7) {
            #pragma unroll
            for (int mi = 0; mi < 4; ++mi) bcur[mi] = bnxt[mi];
        }
    }

    // epilogue: E = exp(2*cos); row sums + own-class bf16 scatter
    int colL = lane & 15, rgrp = (lane >> 4) * 4;
    int cls = mt >> 1;
    int cib = (mt & 1) * 256 + mq * 64 + colL;   // col within the class's 512-block
    float racc[4][4];
    #pragma unroll
    for (int ni = 0; ni < 4; ++ni)
        #pragma unroll
        for (int r = 0; r < 4; ++r) racc[ni][r] = 0.f;
    #pragma unroll
    for (int ni = 0; ni < 4; ++ni)
        #pragma unroll
        for (int r = 0; r < 4; ++r) {
            int row = nh * 64 + ni * 16 + rgrp + r;
            bool sel = (lab_s[row] == cls);
            size_t ebase = (size_t)(n0 + row) * 512 + cib;
            #pragma unroll
            for (int mi = 0; mi < 4; ++mi) {
                float e = __expf(2.0f * acc[ni][mi][r]);
                racc[ni][r] += e;
                if (sel) classbuf[ebase + mi * 16] = __float2bfloat16(e);
            }
        }

    #pragma unroll
    for (int ni = 0; ni < 4; ++ni)
        #pragma unroll
        for (int r = 0; r < 4; ++r) {
            float s = racc[ni][r];
            s += __shfl_xor(s, 1, 64);
            s += __shfl_xor(s, 2, 64);
            s += __shfl_xor(s, 4, 64);
            s += __shfl_xor(s, 8, 64);
            if (colL == 0) totals_s[mq][nh * 64 + ni * 16 + rgrp + r] = s;
        }
    __syncthreads();
    if (t < 128)
        atomicAdd(&total[n0 + t],
                  totals_s[0][t] + totals_s[1][t] + totals_s[2][t] + totals_s[3][t]);
}

// ---------------- kernel 3: per-pixel terms + class bins + fused final ----------
__global__ __launch_bounds__(512) void k_terms(const __hip_bfloat16* __restrict__ classbuf,
                                               const float* __restrict__ total,
                                               const int* __restrict__ labels,
                                               const int* __restrict__ mask,
                                               const int* __restrict__ wmem,
                                               int* __restrict__ done,
                                               float* __restrict__ class_sum,
                                               int* __restrict__ class_cnt,
                                               float* __restrict__ out) {
    __shared__ float csum_s[C_];
    __shared__ int ccnt_s[C_];
    int t = threadIdx.x, ws = t >> 6, lane = t & 63;
    int n0 = blockIdx.x * 64;
    if (t < C_) { csum_s[t] = 0.f; ccnt_s[t] = 0; }
    __syncthreads();

    for (int q = 0; q < 8; ++q) {
        int n = n0 + ws * 8 + q;
        if (!mask[n]) continue;
        int wm = wmem[n];
        int lab = labels[n];
        bf16x8 ev = *(const bf16x8*)&classbuf[(size_t)n * 512 + lane * 8];
        float vv[8];
        #pragma unroll
        for (int u = 0; u < 8; ++u) vv[u] = (float)ev[u];
        float bs = vv[0] + vv[1] + vv[2] + vv[3] + vv[4] + vv[5] + vv[6] + vv[7];
        #pragma unroll
        for (int off = 1; off < 64; off <<= 1) bs += __shfl_xor(bs, off, 64);
        float down = total[n] - bs;
        int lo = (wm == 1) ? 0 : 32;                // wm==1 -> first half [0,S)
        float ts = 0.f;
        if (lane >= lo && lane < lo + 32) {
            #pragma unroll
            for (int u = 0; u < 8; ++u) {
                float pv = vv[u];
                ts += -logf(pv / (pv + down + 1e-12f) + 1e-12f);
            }
        }
        #pragma unroll
        for (int off = 1; off < 64; off <<= 1) ts += __shfl_xor(ts, off, 64);
        if (lane == 0) {
            atomicAdd(&csum_s[lab], ts);
            atomicAdd(&ccnt_s[lab], 1);
        }
    }
    __syncthreads();
    if (t < C_) {
        if (ccnt_s[t] > 0) {
            atomicAdd(&class_sum[t], csum_s[t]);
            atomicAdd(&class_cnt[t], ccnt_s[t]);
        }
    }
    __syncthreads();
    if (t == 0) {
        __threadfence();
        int old = atomicAdd(done, 1);
        if (old == T_BLOCKS - 1) {
            float loss = 0.f, kc = 0.f;
            for (int c = 0; c < C_; ++c) {
                int cn = atomicAdd(&class_cnt[c], 0);
                float sc = atomicAdd(&class_sum[c], 0.f);
                if (cn > 0) { loss += sc / ((float)cn * (float)S_); kc += 1.f; }
            }
            out[0] = loss / fmaxf(kc, 1.f);
        }
    }
}

extern "C" void kernel_launch(void* const* d_in, const int* in_sizes, int n_in,
                              void* d_out, int out_size, void* d_ws, size_t ws_size,
                              hipStream_t stream) {
    const float* mem    = (const float*)d_in[0];
    const float* pred   = (const float*)d_in[1];
    const int*   labels = (const int*)  d_in[2];
    const int*   mask   = (const int*)  d_in[3];
    const int*   wmem   = (const int*)  d_in[4];
    float* out = (float*)d_out;

    float* ws = (float*)d_ws;
    float* total     = ws;                            // N_ floats (memset 0)
    int*   ctrl      = (int*)(ws + N_);               // 40 words (zeroed by prep)
    int*   done      = ctrl;                          // 1
    float* class_sum = (float*)(ctrl + 1);            // 19
    int*   class_cnt = ctrl + 20;                     // 19
    __hip_bfloat16* classbuf = (__hip_bfloat16*)(ws + 16424);    // 16.78 MB bf16
    __hip_bfloat16* A16f = (__hip_bfloat16*)(ws + 4210728);      // 8 MB (frag order)
    __hip_bfloat16* B16  = (__hip_bfloat16*)(ws + 6307880);      // 4.98 MB (frag order)

    hipMemsetAsync(total, 0, N_ * sizeof(float), stream);

    k_prep<<<256 + M_ / 4, 256, 0, stream>>>(pred, mem, A16f, B16, ctrl);

    k_pass1<<<GEMM_BLKS, 512, 0, stream>>>(A16f, B16, labels, total, classbuf);

    k_terms<<<T_BLOCKS, 512, 0, stream>>>(classbuf, total, labels, mask, wmem,
                                          done, class_sum, class_cnt, out);
}